// Round 9
// baseline (1119.987 us; speedup 1.0000x reference)
//
#include <hip/hip_runtime.h>

// CRF log-likelihood, round 9: barrier-free paired-chain scan.
// One 64-thread wave = 2 independent chains (2 sorted 16-batch groups, same
// direction, SHARED A-fragments). Per chain-step: full 128x128 matvec =
// 32x mfma_f32_16x16x32_bf16; D->B transpose via within-wave LDS round-trip
// (write D-layout 8x b64, read B-layout 4x b128; in-order DS pipe, NO
// s_barrier anywhere in the loop). The second chain's MFMAs/VALU fill the
// first chain's pipe stalls and latency bubbles (one wave = one in-order
// issue stream; cross-chain independence gives the scheduler material).
// Lag-1 renorm c=rcp(S0_prev) (lag-2 is UNSTABLE: x_t=x_{t-1}-x_{t-3} has
// |root|>1 -> r8's NaN), exact scale in Dacc (log2). q packed bf16 RTZ
// (1 v_perm/word; ~0.2% downward bias -> absmax ~1 vs threshold 108).
// u via distance-1 register ring (slack ~1 double-step > HBM latency).
// Grid: blocks 0..7 fwd pairs, 8..15 bwd pairs, 16..271 per-batch scores.
// Layouts: A(m,k) m=lane&15,k=quad*8+jj per 32-chunk; B(k,n) n=lane&15,
// k=quad*8+jj; D(m,n) n=lane&15, m=mt*16+quad*4+reg  [r3/r4 absmax-0].

#define B_   256
#define LL   1024
#define TT   128
#define L2E  1.4426950408889634f
#define LN2f 0.6931471805599453f
#define QROW 136   // shorts per LDS q row (128 + 8 pad)

typedef __attribute__((ext_vector_type(8))) short bf16x8;
typedef __attribute__((ext_vector_type(4))) float f32x4;
union bfrw { unsigned w[4]; bf16x8 v; };

__device__ __forceinline__ unsigned bfround(float x) {   // RNE bf16 bits [31:16]
    unsigned u = __float_as_uint(x);
    return u + 0x7fffu + ((u >> 16) & 1u);
}
__device__ __forceinline__ int bperm(int idx, float v) {
    return __builtin_amdgcn_ds_bpermute(idx, __float_as_int(v));
}
__device__ __forceinline__ void wave_fence() {
    asm volatile("s_waitcnt lgkmcnt(0)" ::: "memory");
}

struct ChainS {
    float4 ring[8];      // u for the current step (distance-1 prefetch)
    float  Dacc, s0c;
    int    tfin, cb, rank;
    const float* pu;     // per-lane batch base (inputs + ob*LL*TT)
    short* qb;           // LDS q buffer (16 rows x QROW shorts)
    float* cap;          // qcap (fwd) / rcap (bwd)
    float* dcap;         // dqv / drv
};

template<bool FWD>
__device__ __forceinline__ void cstep(int t, ChainS& S,
                                      const bf16x8 (&af)[8][4],
                                      int quad, int bl)
{
    // ---- B fragments from LDS (q of previous step, batch row bl) ----
    bfrw bfr[4];
    #pragma unroll
    for (int kc = 0; kc < 4; ++kc)
        bfr[kc].v = *(const bf16x8*)(S.qb + bl * QROW + kc * 32 + quad * 8);

    float ci = __builtin_amdgcn_rcpf(S.s0c);
    S.Dacc += __builtin_amdgcn_logf(S.s0c);            // v_log_f32 = log2

    // ---- 32 MFMA (8 independent depth-4 chains) ----
    f32x4 acc[8];
    #pragma unroll
    for (int mt = 0; mt < 8; ++mt) acc[mt] = (f32x4){0.f, 0.f, 0.f, 0.f};
    #pragma unroll
    for (int kc = 0; kc < 4; ++kc) {
        #pragma unroll
        for (int mt = 0; mt < 8; ++mt)
            acc[mt] = __builtin_amdgcn_mfma_f32_16x16x32_bf16(
                af[mt][kc], bfr[kc].v, acc[mt], 0, 0, 0);
    }

    // ---- exp of this step's u (ring), then reload ring for next step ----
    float ex[32];
    #pragma unroll
    for (int mt = 0; mt < 8; ++mt) {
        float4 v = S.ring[mt];
        ex[4*mt+0] = __builtin_amdgcn_exp2f(v.x * L2E);
        ex[4*mt+1] = __builtin_amdgcn_exp2f(v.y * L2E);
        ex[4*mt+2] = __builtin_amdgcn_exp2f(v.z * L2E);
        ex[4*mt+3] = __builtin_amdgcn_exp2f(v.w * L2E);
    }
    {
        int ui = FWD ? (t + 1) : (t - 2);
        if (ui < 0) ui = 0;
        #pragma unroll
        for (int mt = 0; mt < 8; ++mt)
            S.ring[mt] = *(const float4*)(S.pu + (size_t)ui * TT + mt * 16 + quad * 4);
    }

    // raw S0 = s[j=0] (mt0,reg0 on quad-0 lane bl) -> all lanes, for next step
    float s0n = __int_as_float(bperm(4 * bl, acc[0][0]));

    float ov[32];
    if (FWD) {
        #pragma unroll
        for (int mt = 0; mt < 8; ++mt) {
            #pragma unroll
            for (int r = 0; r < 4; ++r)
                ov[4*mt+r] = ex[4*mt+r] * (ci * acc[mt][r]);
        }
        bool cap = (S.cb == t);
        if (__any(cap)) {
            if (cap) {
                #pragma unroll
                for (int mt = 0; mt < 8; ++mt) {
                    float4 c4 = {ov[4*mt+0], ov[4*mt+1], ov[4*mt+2], ov[4*mt+3]};
                    *(float4*)(S.cap + (size_t)S.rank * TT + mt * 16 + quad * 4) = c4;
                }
                if (quad == 0) S.dcap[S.rank] = S.Dacc;
            }
        }
    } else {
        float rv[32];
        #pragma unroll
        for (int mt = 0; mt < 8; ++mt) {
            #pragma unroll
            for (int r = 0; r < 4; ++r)
                rv[4*mt+r] = ci * acc[mt][r];
        }
        bool cap = (S.cb == t - 1) && (S.cb != S.tfin);
        if (__any(cap)) {
            if (cap) {
                #pragma unroll
                for (int mt = 0; mt < 8; ++mt) {
                    float4 c4 = {rv[4*mt+0], rv[4*mt+1], rv[4*mt+2], rv[4*mt+3]};
                    *(float4*)(S.cap + (size_t)S.rank * TT + mt * 16 + quad * 4) = c4;
                }
                if (quad == 0) S.dcap[S.rank] = S.Dacc;
            }
        }
        bool inj = (S.tfin == t - 1);
        #pragma unroll
        for (int k = 0; k < 32; ++k) ov[k] = inj ? ex[k] : ex[k] * rv[k];
        S.Dacc = inj ? 0.f : S.Dacc;
    }
    S.s0c = s0n;

    // ---- pack (RTZ: 1 v_perm per word) and write D-layout rows ----
    #pragma unroll
    for (int mt = 0; mt < 8; ++mt) {
        uint2 w;
        w.x = __builtin_amdgcn_perm(__float_as_uint(ov[4*mt+1]),
                                    __float_as_uint(ov[4*mt+0]), 0x07060302);
        w.y = __builtin_amdgcn_perm(__float_as_uint(ov[4*mt+3]),
                                    __float_as_uint(ov[4*mt+2]), 0x07060302);
        *(uint2*)(S.qb + bl * QROW + mt * 16 + quad * 4) = w;
    }
}

__launch_bounds__(64, 1)
__global__ void crf_scan(const float* __restrict__ inputs,
                         const int*   __restrict__ tags,
                         const int*   __restrict__ slens,
                         const float* __restrict__ trans,
                         float* __restrict__ qcap, float* __restrict__ rcap,
                         float* __restrict__ dqv,  float* __restrict__ drv,
                         int* __restrict__ perm, float* __restrict__ scorebuf)
{
    const int tid = threadIdx.x;

    // ---------------- score blocks (16..271): one batch each ----------------
    if (blockIdx.x >= 16) {
        const int b = blockIdx.x - 16;
        const int slen = slens[b];
        const float* inb  = inputs + (size_t)b * LL * TT;
        const int*   tagb = tags + b * LL;
        float sc = 0.f;
        for (int t = tid; t < slen; t += 64) {
            int tg = tagb[t];
            float v = inb[(size_t)t * TT + tg];
            if (t >= 1) v += trans[tagb[t - 1] * TT + tg];
            sc += v;
        }
        #pragma unroll
        for (int off = 32; off > 0; off >>= 1) sc += __shfl_xor(sc, off, 64);
        if (tid == 0) scorebuf[b] = sc;
        return;
    }

    // ---------------- scan blocks (0..15) ----------------
    __shared__ int keys[B_];
    __shared__ __align__(16) short qbuf[2][16 * QROW];

    const int quad = tid >> 4;
    const int bl   = tid & 15;
    const bool isf = (blockIdx.x < 8);
    const int p    = isf ? blockIdx.x : blockIdx.x - 8;

    // deterministic bitonic sort of (slen, batch) keys — single wave, no barriers
    #pragma unroll
    for (int i = tid; i < B_; i += 64) keys[i] = slens[i] * 256 + i;
    wave_fence();
    for (int k = 2; k <= B_; k <<= 1) {
        for (int s = k >> 1; s > 0; s >>= 1) {
            #pragma unroll
            for (int e = 0; e < 4; ++e) {
                int i = tid + 64 * e;
                int j = i ^ s;
                if (j > i) {
                    int a = keys[i], b2 = keys[j];
                    bool asc = ((i & k) == 0);
                    if ((a > b2) == asc) { keys[i] = b2; keys[j] = a; }
                }
            }
            wave_fence();
        }
    }
    if (isf && tid < 32) perm[p * 32 + tid] = keys[p * 32 + tid] & 255;

    // ---- per-chain setup (chains = groups 2p, 2p+1) ----
    ChainS CH[2];
    int tb0v[2], cmaxv[2], cminv[2];
    #pragma unroll
    for (int c = 0; c < 2; ++c) {
        const int g   = 2 * p + c;
        const int key = keys[g * 16 + bl];
        const int ob  = key & 255;
        const int sl  = key >> 8;
        int tfin = sl - 1; if (tfin < 1) tfin = 1;
        int tmax = tfin;
        #pragma unroll
        for (int o = 1; o < 16; o <<= 1) {
            int v = __shfl_xor(tmax, o, 16); tmax = v > tmax ? v : tmax;
        }
        tmax = __builtin_amdgcn_readfirstlane(tmax);
        const int C  = (tmax + 4) >> 1;
        const int cb = tfin < C ? tfin : C;
        int cmax = cb, cmin = cb;
        #pragma unroll
        for (int o = 1; o < 16; o <<= 1) {
            int a = __shfl_xor(cmax, o, 16); cmax = a > cmax ? a : cmax;
            int b2 = __shfl_xor(cmin, o, 16); cmin = b2 < cmin ? b2 : cmin;
        }
        cmaxv[c] = __builtin_amdgcn_readfirstlane(cmax);
        cminv[c] = __builtin_amdgcn_readfirstlane(cmin);
        tb0v[c]  = (tmax + 2) & ~1;
        CH[c].tfin = tfin; CH[c].cb = cb; CH[c].rank = g * 16 + bl;
        CH[c].pu   = inputs + (size_t)ob * LL * TT;
        CH[c].qb   = &qbuf[c][0];
        CH[c].cap  = isf ? qcap : rcap;
        CH[c].dcap = isf ? dqv : drv;
        CH[c].Dacc = 0.f; CH[c].s0c = 1.f;
    }

    // ---- shared A fragments (direction-dependent) ----
    bf16x8 af[8][4];
    #pragma unroll
    for (int mt = 0; mt < 8; ++mt) {
        const int j = mt * 16 + bl;
        #pragma unroll
        for (int kc = 0; kc < 4; ++kc) {
            #pragma unroll
            for (int jj = 0; jj < 8; ++jj) {
                int k = kc * 32 + quad * 8 + jj;
                int idx = isf ? (k * TT + j) : (j * TT + k);
                float ev = __builtin_amdgcn_exp2f(trans[idx] * L2E);
                af[mt][kc][jj] = (short)(bfround(ev) >> 16);
            }
        }
    }

    if (isf) {
        // init q0 = exp(in[0][j]) (RNE), ring = u(1)
        #pragma unroll
        for (int c = 0; c < 2; ++c) {
            #pragma unroll
            for (int mt = 0; mt < 8; ++mt) {
                float4 v = *(const float4*)(CH[c].pu + mt * 16 + quad * 4);
                float e0 = __builtin_amdgcn_exp2f(v.x * L2E);
                float e1 = __builtin_amdgcn_exp2f(v.y * L2E);
                float e2 = __builtin_amdgcn_exp2f(v.z * L2E);
                float e3 = __builtin_amdgcn_exp2f(v.w * L2E);
                uint2 w;
                w.x = __builtin_amdgcn_perm(bfround(e1), bfround(e0), 0x07060302);
                w.y = __builtin_amdgcn_perm(bfround(e3), bfround(e2), 0x07060302);
                *(uint2*)(CH[c].qb + bl * QROW + mt * 16 + quad * 4) = w;
                CH[c].ring[mt] = *(const float4*)(CH[c].pu + (size_t)TT + mt * 16 + quad * 4);
            }
        }
        wave_fence();
        const int cmm = cmaxv[0] > cmaxv[1] ? cmaxv[0] : cmaxv[1];
        for (int t = 1; t <= cmm; ++t) {
            cstep<true>(t, CH[0], af, quad, bl);
            cstep<true>(t, CH[1], af, quad, bl);
        }
    } else {
        const int tstart = tb0v[0] > tb0v[1] ? tb0v[0] : tb0v[1];
        const int tend   = cminv[0] < cminv[1] ? cminv[0] : cminv[1];
        #pragma unroll
        for (int c = 0; c < 2; ++c) {
            #pragma unroll
            for (int mt = 0; mt < 8; ++mt) {
                uint2 w; w.x = 0x3F803F80u; w.y = 0x3F803F80u;   // w = 1.0 bf16
                *(uint2*)(CH[c].qb + bl * QROW + mt * 16 + quad * 4) = w;
                int ui = tstart - 1; if (ui > LL - 1) ui = LL - 1;
                CH[c].ring[mt] = *(const float4*)(CH[c].pu + (size_t)ui * TT + mt * 16 + quad * 4);
            }
            if (CH[c].cb == CH[c].tfin) {           // r = ones, Dr = 0 at init
                #pragma unroll
                for (int mt = 0; mt < 8; ++mt) {
                    float4 one4 = {1.f, 1.f, 1.f, 1.f};
                    *(float4*)(CH[c].cap + (size_t)CH[c].rank * TT + mt * 16 + quad * 4) = one4;
                }
                if (quad == 0) CH[c].dcap[CH[c].rank] = 0.f;
            }
        }
        wave_fence();
        for (int t = tstart; t > tend; --t) {
            cstep<false>(t, CH[0], af, quad, bl);
            cstep<false>(t, CH[1], af, quad, bl);
        }
    }
}

__global__ void crf_comb(const float* __restrict__ qcap, const float* __restrict__ rcap,
                         const float* __restrict__ dqv, const float* __restrict__ drv,
                         const int* __restrict__ perm, const float* __restrict__ scorebuf,
                         float* __restrict__ out) {
    const int tid = threadIdx.x;
    const int r16 = tid >> 4, part = tid & 15;
    const int rank = blockIdx.x * 16 + r16;
    const float* qc = qcap + (size_t)rank * TT + part * 8;
    const float* rc = rcap + (size_t)rank * TT + part * 8;
    float4 a0 = *(const float4*)(qc);
    float4 a1 = *(const float4*)(qc + 4);
    float4 b0 = *(const float4*)(rc);
    float4 b1 = *(const float4*)(rc + 4);
    float s = a0.x*b0.x + a0.y*b0.y + a0.z*b0.z + a0.w*b0.w
            + a1.x*b1.x + a1.y*b1.y + a1.z*b1.z + a1.w*b1.w;
    #pragma unroll
    for (int o = 1; o < 16; o <<= 1) s += __shfl_xor(s, o, 16);
    if (part == 0) {
        int ob = perm[rank];
        float logZ = LN2f * (__builtin_amdgcn_logf(s) + dqv[rank] + drv[rank]);
        out[ob] = scorebuf[ob] - logZ;
    }
}

extern "C" void kernel_launch(void* const* d_in, const int* in_sizes, int n_in,
                              void* d_out, int out_size, void* d_ws, size_t ws_size,
                              hipStream_t stream) {
    const float* inputs = (const float*)d_in[0];
    const int*   tags   = (const int*)d_in[1];
    const int*   slens  = (const int*)d_in[2];
    const float* trans  = (const float*)d_in[3];
    float* out = (float*)d_out;

    float* qcap = (float*)d_ws;            // 256*128 f32
    float* rcap = qcap + 32768;            // 256*128 f32
    float* dqv  = rcap + 32768;            // 256
    float* drv  = dqv + 256;               // 256
    int*   perm = (int*)(drv + 256);       // 256
    float* scorebuf = (float*)(perm + 256);// 256

    crf_scan<<<16 + B_, 64, 0, stream>>>(inputs, tags, slens, trans,
                                         qcap, rcap, dqv, drv, perm, scorebuf);
    crf_comb<<<16, 256, 0, stream>>>(qcap, rcap, dqv, drv, perm, scorebuf, out);
}